// Round 4
// baseline (441.691 us; speedup 1.0000x reference)
//
#include <hip/hip_runtime.h>
#include <hip/hip_cooperative_groups.h>
#include <math.h>

namespace cg = cooperative_groups;

#define LP 800
#define DP 200
#define HP 100
#define MP 256   // P*K
#define MM1 255

typedef float fx4 __attribute__((ext_vector_type(4)));

// d_out offsets (floats), reference return order
#define OFF_SCS  0u
#define OFF_R    40960000u
#define OFF_ENC  40985600u
#define OFF_V    41190400u
#define OFF_TIL  41255680u

// workspace offsets (floats)
#define WS_O     0u        // 25600
#define WS_E     25600u    // 65280
#define WS_S     90880u    // 65280  (s_rows, row-major [i][jp])

__device__ __forceinline__ float tanh_fast(float x) {
    // tanh(x) = 1 - 2/(exp(2x)+1); exact at both saturation ends.
    float e = __expf(2.0f * x);
    return 1.0f - 2.0f / (e + 1.0f);
}

// ---------------- Kernel A: S_Cs masked stream copy (fx4, NT stores) ----
__global__ __launch_bounds__(256) void scs_kernel(const fx4* __restrict__ Sp4,
                                                  const int* __restrict__ spans,
                                                  fx4* __restrict__ out4) {
    int m = blockIdx.y;
    int off = blockIdx.x * blockDim.x + threadIdx.x;
    if (off >= 40000) return;
    int p = m >> 1, k = m & 1;
    int start = spans[p * 4 + k * 2];
    int end   = spans[p * 4 + k * 2 + 1];
    int t = off / 50;   // 50 fx4 per D-row
    fx4 v = (fx4)(0.f);
    if (t >= start && t <= end) v = Sp4[p * 40000 + off];
    __builtin_nontemporal_store(v, &out4[m * 40000 + off]);
}

// ---------------- Kernel B: whole small chain, one cooperative kernel ------
// Phase 0 (block=m): enc, r, c(local), o
// Phase 1 (block=i): V + E
// Phase 2 (block=jp<255): colE -> alpha -> s_rows
// Phase 3 (block=i): tilda
__global__ __launch_bounds__(256) void chain_kernel(const float* __restrict__ Sp,
                                                    const int* __restrict__ spans,
                                                    const int* __restrict__ passages,
                                                    const float* __restrict__ Wb,
                                                    const float* __restrict__ We,
                                                    const float* __restrict__ Wc,
                                                    const float* __restrict__ Wo,
                                                    const float* __restrict__ Wv,
                                                    float* __restrict__ enc,
                                                    float* __restrict__ r_out,
                                                    float* __restrict__ V_out,
                                                    float* __restrict__ til_out,
                                                    float* __restrict__ o_ws,
                                                    float* __restrict__ e_ws,
                                                    float* __restrict__ s_ws) {
    cg::grid_group grid = cg::this_grid();
    __shared__ float4 sb4[50], se4[50], rs4[25], cl4[25], wv4[25];
    __shared__ float srow[MM1 + 1];
    __shared__ float part[4];

    int bid = blockIdx.x;
    int tid = threadIdx.x;

    // ---------------- Phase 0: enc + r + c(local) + o, m = bid ------------
    {
        int m = bid;
        int p = m >> 1, k = m & 1;
        int start = spans[p * 4 + k * 2];
        int end   = spans[p * 4 + k * 2 + 1];

        int len = end - start;
        for (int t = tid; t < LP; t += 256) {
            int g = start + t; if (g > LP - 1) g = LP - 1;
            enc[m * LP + t] = (t <= len) ? (float)passages[p * LP + g] : 0.f;
        }

        const float4* sbp = (const float4*)(Sp + (size_t)(p * LP + start) * DP);
        const float4* sep = (const float4*)(Sp + (size_t)(p * LP + end) * DP);
        if (tid < 50)       sb4[tid]      = sbp[tid];
        else if (tid < 100) se4[tid - 50] = sep[tid - 50];
        if (tid >= 100 && tid < 125) wv4[tid - 100] = ((const float4*)Wv)[tid - 100];
        __syncthreads();

        int h = tid;
        if (h < HP) {
            const float4* wb = (const float4*)(Wb + h * DP);
            const float4* we = (const float4*)(We + h * DP);
            float acc = 0.f;
            #pragma unroll
            for (int d = 0; d < 50; ++d) {
                float4 a = sb4[d], b = wb[d];
                acc += a.x * b.x + a.y * b.y + a.z * b.z + a.w * b.w;
                float4 a2 = se4[d], b2 = we[d];
                acc += a2.x * b2.x + a2.y * b2.y + a2.z * b2.z + a2.w * b2.w;
            }
            float r = tanh_fast(acc);
            ((float*)rs4)[h] = r;
            r_out[m * HP + h] = r;
        }
        __syncthreads();
        if (h < HP) {
            const float4* wc = (const float4*)(Wc + h * HP);
            const float4* wo = (const float4*)(Wo + h * HP);
            float accc = 0.f, acco = 0.f;
            #pragma unroll
            for (int q = 0; q < 25; ++q) {
                float4 r = rs4[q], cc = wc[q], oo = wo[q];
                accc += r.x * cc.x + r.y * cc.y + r.z * cc.z + r.w * cc.w;
                acco += r.x * oo.x + r.y * oo.y + r.z * oo.z + r.w * oo.w;
            }
            ((float*)cl4)[h] = accc;   // c row i stays local to this block
            o_ws[m * HP + h] = acco;
        }
    }
    __threadfence();
    grid.sync();

    // ---------------- Phase 1: V + E, i = bid ------------------------------
    {
        int i = bid;
        int jp = tid;
        if (jp < MM1) {
            int j = jp + (jp >= i ? 1 : 0);
            const float4* oj = (const float4*)(o_ws + j * HP);
            float acc = 0.f;
            #pragma unroll
            for (int q = 0; q < 25; ++q) {
                float4 o4 = oj[q], c4 = cl4[q], w4 = wv4[q];
                acc += tanh_fast(c4.x + o4.x) * w4.x;
                acc += tanh_fast(c4.y + o4.y) * w4.y;
                acc += tanh_fast(c4.z + o4.z) * w4.z;
                acc += tanh_fast(c4.w + o4.w) * w4.w;
            }
            V_out[i * MM1 + jp] = acc;
            e_ws[i * MM1 + jp] = __expf(acc);
        }
    }
    __threadfence();
    grid.sync();

    // ---------------- Phase 2: alpha -> s_rows, jp = bid < 255 -------------
    if (bid < MM1) {
        int jp = bid;
        int i = tid;
        float e = e_ws[i * MM1 + jp];

        float v = e;
        v += __shfl_down(v, 32); v += __shfl_down(v, 16); v += __shfl_down(v, 8);
        v += __shfl_down(v, 4);  v += __shfl_down(v, 2);  v += __shfl_down(v, 1);
        if ((i & 63) == 0) part[i >> 6] = v;
        __syncthreads();
        float colE = part[0] + part[1] + part[2] + part[3];

        float a = e / (colE - e);

        __syncthreads();
        float v2 = a;
        v2 += __shfl_down(v2, 32); v2 += __shfl_down(v2, 16); v2 += __shfl_down(v2, 8);
        v2 += __shfl_down(v2, 4);  v2 += __shfl_down(v2, 2);  v2 += __shfl_down(v2, 1);
        if ((i & 63) == 0) part[i >> 6] = v2;
        __syncthreads();
        float colA = part[0] + part[1] + part[2] + part[3];

        s_ws[i * MM1 + jp] = colA - a;
    }
    __threadfence();
    grid.sync();

    // ---------------- Phase 3: tilda, i = bid ------------------------------
    {
        int i = bid;
        for (int jp = tid; jp < MM1; jp += 256)
            srow[jp] = s_ws[i * MM1 + jp];
        __syncthreads();
        int h = tid;
        if (h < HP) {
            float acc = 0.f;
            #pragma unroll 4
            for (int jp = 0; jp < i; ++jp)
                acc += srow[jp] * r_out[jp * HP + h];
            #pragma unroll 4
            for (int jp = i; jp < MM1; ++jp)
                acc += srow[jp] * r_out[(jp + 1) * HP + h];
            til_out[i * HP + h] = acc;
        }
    }
}

extern "C" void kernel_launch(void* const* d_in, const int* in_sizes, int n_in,
                              void* d_out, int out_size, void* d_ws, size_t ws_size,
                              hipStream_t stream) {
    const float* S_p      = (const float*)d_in[0];
    const int*   spans    = (const int*)d_in[1];
    const int*   passages = (const int*)d_in[2];
    const float* Wb       = (const float*)d_in[3];
    const float* We       = (const float*)d_in[4];
    const float* Wc       = (const float*)d_in[5];
    const float* Wo       = (const float*)d_in[6];
    const float* Wv       = (const float*)d_in[7];

    float* out = (float*)d_out;
    float* ws  = (float*)d_ws;

    float* out_scs = out + OFF_SCS;
    float* out_r   = out + OFF_R;
    float* out_enc = out + OFF_ENC;
    float* out_v   = out + OFF_V;
    float* out_til = out + OFF_TIL;

    float* ws_o = ws + WS_O;
    float* ws_e = ws + WS_E;
    float* ws_s = ws + WS_S;

    void* args[] = {
        (void*)&S_p, (void*)&spans, (void*)&passages,
        (void*)&Wb, (void*)&We, (void*)&Wc, (void*)&Wo, (void*)&Wv,
        (void*)&out_enc, (void*)&out_r, (void*)&out_v, (void*)&out_til,
        (void*)&ws_o, (void*)&ws_e, (void*)&ws_s
    };
    hipLaunchCooperativeKernel((void*)chain_kernel, dim3(MP), dim3(256),
                               args, 0, stream);

    dim3 gridA((40000 + 255) / 256, MP);
    scs_kernel<<<gridA, 256, 0, stream>>>((const fx4*)S_p, spans, (fx4*)out_scs);
}

// Round 5
// 276.907 us; speedup vs baseline: 1.5951x; 1.5951x over previous
//
#include <hip/hip_runtime.h>
#include <math.h>

#define LP 800
#define DP 200
#define HP 100
#define MP 256   // P*K
#define MM1 255

typedef float fx4 __attribute__((ext_vector_type(4)));

// d_out offsets (floats), reference return order
#define OFF_SCS  0u
#define OFF_R    40960000u
#define OFF_ENC  40985600u
#define OFF_V    41190400u
#define OFF_TIL  41255680u

// workspace offsets (floats)
#define WS_C     0u        // 25600
#define WS_O     25600u    // 25600
#define WS_S     51200u    // 65280  (s_rows, row-major [i][jp])

__device__ __forceinline__ float tanh_fast(float x) {
    // tanh(x) = 1 - 2/(exp(2x)+1); exact at both saturation ends.
    float e = __expf(2.0f * x);
    return 1.0f - 2.0f / (e + 1.0f);
}

// ---------------- Kernel A: S_Cs masked stream copy (fx4, NT stores) ----
__global__ __launch_bounds__(256) void scs_kernel(const fx4* __restrict__ Sp4,
                                                  const int* __restrict__ spans,
                                                  fx4* __restrict__ out4) {
    int m = blockIdx.y;
    int off = blockIdx.x * blockDim.x + threadIdx.x;
    if (off >= 40000) return;
    int p = m >> 1, k = m & 1;
    int start = spans[p * 4 + k * 2];
    int end   = spans[p * 4 + k * 2 + 1];
    int t = off / 50;   // 50 fx4 per D-row
    fx4 v = (fx4)(0.f);
    if (t >= start && t <= end) v = Sp4[p * 40000 + off];
    __builtin_nontemporal_store(v, &out4[m * 40000 + off]);
}

// ---------------- Kernel B: enc + r_Cs + c + o fused (one block per m) -----
__global__ __launch_bounds__(256) void encrco_kernel(const float* __restrict__ Sp,
                                                     const int* __restrict__ spans,
                                                     const int* __restrict__ passages,
                                                     const float* __restrict__ Wb,
                                                     const float* __restrict__ We,
                                                     const float* __restrict__ Wc,
                                                     const float* __restrict__ Wo,
                                                     float* __restrict__ enc,
                                                     float* __restrict__ r_out,
                                                     float* __restrict__ c_ws,
                                                     float* __restrict__ o_ws) {
    __shared__ float4 sb4[50], se4[50], rs4[25];
    int m = blockIdx.x;
    int p = m >> 1, k = m & 1;
    int start = spans[p * 4 + k * 2];
    int end   = spans[p * 4 + k * 2 + 1];
    int tid = threadIdx.x;

    // encoded_candidates (ints exact in f32)
    int len = end - start;
    for (int t = tid; t < LP; t += 256) {
        int g = start + t; if (g > LP - 1) g = LP - 1;
        enc[m * LP + t] = (t <= len) ? (float)passages[p * LP + g] : 0.f;
    }

    // stage sb/se rows (16B-aligned: row stride 800 B)
    const float4* sbp = (const float4*)(Sp + (size_t)(p * LP + start) * DP);
    const float4* sep = (const float4*)(Sp + (size_t)(p * LP + end) * DP);
    if (tid < 50)       sb4[tid]      = sbp[tid];
    else if (tid < 100) se4[tid - 50] = sep[tid - 50];
    __syncthreads();

    int h = tid;
    if (h < HP) {
        const float4* wb = (const float4*)(Wb + h * DP);
        const float4* we = (const float4*)(We + h * DP);
        float acc = 0.f;
        #pragma unroll
        for (int d = 0; d < 50; ++d) {
            float4 a = sb4[d], b = wb[d];
            acc += a.x * b.x + a.y * b.y + a.z * b.z + a.w * b.w;
            float4 a2 = se4[d], b2 = we[d];
            acc += a2.x * b2.x + a2.y * b2.y + a2.z * b2.z + a2.w * b2.w;
        }
        float r = tanh_fast(acc);
        ((float*)rs4)[h] = r;
        r_out[m * HP + h] = r;
    }
    __syncthreads();
    if (h < HP) {
        const float4* wc = (const float4*)(Wc + h * HP);
        const float4* wo = (const float4*)(Wo + h * HP);
        float accc = 0.f, acco = 0.f;
        #pragma unroll
        for (int q = 0; q < 25; ++q) {
            float4 r = rs4[q], cc = wc[q], oo = wo[q];
            accc += r.x * cc.x + r.y * cc.y + r.z * cc.z + r.w * cc.w;
            acco += r.x * oo.x + r.y * oo.y + r.z * oo.z + r.w * oo.w;
        }
        c_ws[m * HP + h] = accc;
        o_ws[m * HP + h] = acco;
    }
}

// ---------------- Kernel C: V + E + alpha + s_rows, column-wise ------------
// one block per column jp (255 blocks), thread i in [0,256).
// j = jp + (jp >= i): only two o-rows per column -> LDS.
__global__ __launch_bounds__(256) void vcol_kernel(const float* __restrict__ c_ws,
                                                   const float* __restrict__ o_ws,
                                                   const float* __restrict__ Wv,
                                                   float* __restrict__ V_out,
                                                   float* __restrict__ s_ws) {
    __shared__ float4 olo4[25], ohi4[25], wv4[25];
    __shared__ float part[4];
    int jp = blockIdx.x;
    int i = threadIdx.x;
    if (i < 25) {
        olo4[i] = ((const float4*)(o_ws + jp * HP))[i];
        ohi4[i] = ((const float4*)(o_ws + (jp + 1) * HP))[i];
        wv4[i]  = ((const float4*)Wv)[i];
    }
    __syncthreads();

    const float4* c4p = (const float4*)(c_ws + i * HP);
    bool hi = (jp >= i);   // i <= jp -> j = jp+1
    float acc = 0.f;
    #pragma unroll
    for (int q = 0; q < 25; ++q) {
        float4 c4 = c4p[q];
        float4 o4 = hi ? ohi4[q] : olo4[q];
        float4 w4 = wv4[q];
        acc += tanh_fast(c4.x + o4.x) * w4.x;
        acc += tanh_fast(c4.y + o4.y) * w4.y;
        acc += tanh_fast(c4.z + o4.z) * w4.z;
        acc += tanh_fast(c4.w + o4.w) * w4.w;
    }
    V_out[i * MM1 + jp] = acc;
    float e = __expf(acc);

    // colE = sum_i e (deterministic block reduce)
    float v = e;
    v += __shfl_down(v, 32); v += __shfl_down(v, 16); v += __shfl_down(v, 8);
    v += __shfl_down(v, 4);  v += __shfl_down(v, 2);  v += __shfl_down(v, 1);
    if ((i & 63) == 0) part[i >> 6] = v;
    __syncthreads();
    float colE = part[0] + part[1] + part[2] + part[3];

    float a = e / (colE - e);

    __syncthreads();
    float v2 = a;
    v2 += __shfl_down(v2, 32); v2 += __shfl_down(v2, 16); v2 += __shfl_down(v2, 8);
    v2 += __shfl_down(v2, 4);  v2 += __shfl_down(v2, 2);  v2 += __shfl_down(v2, 1);
    if ((i & 63) == 0) part[i >> 6] = v2;
    __syncthreads();
    float colA = part[0] + part[1] + part[2] + part[3];

    s_ws[i * MM1 + jp] = colA - a;
}

// ---------------- Kernel D: tilda_r_Cs ----------------
__global__ __launch_bounds__(128) void tilda_kernel(const float* __restrict__ s_ws,
                                                    const float* __restrict__ r_out,
                                                    float* __restrict__ til_out) {
    __shared__ float s[MM1 + 1];
    int i = blockIdx.x;
    for (int jp = threadIdx.x; jp < MM1; jp += 128)
        s[jp] = s_ws[i * MM1 + jp];
    __syncthreads();
    int h = threadIdx.x;
    if (h < HP) {
        float acc = 0.f;
        #pragma unroll 4
        for (int jp = 0; jp < i; ++jp)
            acc += s[jp] * r_out[jp * HP + h];
        #pragma unroll 4
        for (int jp = i; jp < MM1; ++jp)
            acc += s[jp] * r_out[(jp + 1) * HP + h];
        til_out[i * HP + h] = acc;
    }
}

extern "C" void kernel_launch(void* const* d_in, const int* in_sizes, int n_in,
                              void* d_out, int out_size, void* d_ws, size_t ws_size,
                              hipStream_t stream) {
    const float* S_p      = (const float*)d_in[0];
    const int*   spans    = (const int*)d_in[1];
    const int*   passages = (const int*)d_in[2];
    const float* Wb       = (const float*)d_in[3];
    const float* We       = (const float*)d_in[4];
    const float* Wc       = (const float*)d_in[5];
    const float* Wo       = (const float*)d_in[6];
    const float* Wv       = (const float*)d_in[7];

    float* out = (float*)d_out;
    float* ws  = (float*)d_ws;

    float* out_scs = out + OFF_SCS;
    float* out_r   = out + OFF_R;
    float* out_enc = out + OFF_ENC;
    float* out_v   = out + OFF_V;
    float* out_til = out + OFF_TIL;

    float* ws_c = ws + WS_C;
    float* ws_o = ws + WS_O;
    float* ws_s = ws + WS_S;

    // small chain first, then the big stream
    encrco_kernel<<<MP, 256, 0, stream>>>(S_p, spans, passages, Wb, We, Wc, Wo,
                                          out_enc, out_r, ws_c, ws_o);
    vcol_kernel<<<MM1, 256, 0, stream>>>(ws_c, ws_o, Wv, out_v, ws_s);
    tilda_kernel<<<MP, 128, 0, stream>>>(ws_s, out_r, out_til);

    dim3 gridA((40000 + 255) / 256, MP);
    scs_kernel<<<gridA, 256, 0, stream>>>((const fx4*)S_p, spans, (fx4*)out_scs);
}

// Round 6
// 267.083 us; speedup vs baseline: 1.6538x; 1.0368x over previous
//
#include <hip/hip_runtime.h>
#include <math.h>

#define LP 800
#define DP 200
#define HP 100
#define MP 256   // P*K
#define MM1 255

typedef float fx4 __attribute__((ext_vector_type(4)));

// d_out offsets (floats), reference return order
#define OFF_SCS  0u
#define OFF_R    40960000u
#define OFF_ENC  40985600u
#define OFF_V    41190400u
#define OFF_TIL  41255680u

// workspace offsets (floats)
#define WS_C     0u        // 25600
#define WS_O     25600u    // 25600
#define WS_S     51200u    // 65280  (s_rows, row-major [i][jp])

// scs flat units: 256 m * 40000 fx4 = 10.24M units, 256 units per block
// => 40000 scs block-units split across the 3 chain nodes.
#define SCS_B1 13334
#define SCS_B2 13333
#define SCS_B3 13333
#define NB1 0
#define NB2 13334
#define NB3 26667

__device__ __forceinline__ float tanh_fast(float x) {
    // tanh(x) = 1 - 2/(exp(2x)+1); exact at both saturation ends.
    float e = __expf(2.0f * x);
    return 1.0f - 2.0f / (e + 1.0f);
}

// one block-unit of the S_Cs masked stream copy (256 fx4, one per thread)
__device__ __forceinline__ void scs_slice(const fx4* __restrict__ Sp4,
                                          const int* __restrict__ spans,
                                          fx4* __restrict__ out4,
                                          unsigned ubase) {
    unsigned u = ubase * 256u + threadIdx.x;
    unsigned m = u / 40000u;
    unsigned off = u - m * 40000u;
    unsigned p = m >> 1, k = m & 1;
    int start = spans[p * 4 + k * 2];
    int end   = spans[p * 4 + k * 2 + 1];
    int t = (int)(off / 50u);   // 50 fx4 per D-row
    fx4 v = (fx4)(0.f);
    if (t >= start && t <= end) v = Sp4[p * 40000u + off];
    __builtin_nontemporal_store(v, &out4[m * 40000u + off]);
}

// ---------------- Node 1: enc + r + c + o (blocks 0..255) + scs slice ------
__global__ __launch_bounds__(256) void node1_kernel(const float* __restrict__ Sp,
                                                    const int* __restrict__ spans,
                                                    const int* __restrict__ passages,
                                                    const float* __restrict__ Wb,
                                                    const float* __restrict__ We,
                                                    const float* __restrict__ Wc,
                                                    const float* __restrict__ Wo,
                                                    float* __restrict__ enc,
                                                    float* __restrict__ r_out,
                                                    float* __restrict__ c_ws,
                                                    float* __restrict__ o_ws,
                                                    fx4* __restrict__ out4) {
    if (blockIdx.x >= MP) {
        scs_slice((const fx4*)Sp, spans, out4, NB1 + blockIdx.x - MP);
        return;
    }
    __shared__ float4 sb4[50], se4[50], rs4[25];
    int m = blockIdx.x;
    int p = m >> 1, k = m & 1;
    int start = spans[p * 4 + k * 2];
    int end   = spans[p * 4 + k * 2 + 1];
    int tid = threadIdx.x;

    int len = end - start;
    for (int t = tid; t < LP; t += 256) {
        int g = start + t; if (g > LP - 1) g = LP - 1;
        enc[m * LP + t] = (t <= len) ? (float)passages[p * LP + g] : 0.f;
    }

    const float4* sbp = (const float4*)(Sp + (size_t)(p * LP + start) * DP);
    const float4* sep = (const float4*)(Sp + (size_t)(p * LP + end) * DP);
    if (tid < 50)       sb4[tid]      = sbp[tid];
    else if (tid < 100) se4[tid - 50] = sep[tid - 50];
    __syncthreads();

    int h = tid;
    if (h < HP) {
        const float4* wb = (const float4*)(Wb + h * DP);
        const float4* we = (const float4*)(We + h * DP);
        float acc = 0.f;
        #pragma unroll
        for (int d = 0; d < 50; ++d) {
            float4 a = sb4[d], b = wb[d];
            acc += a.x * b.x + a.y * b.y + a.z * b.z + a.w * b.w;
            float4 a2 = se4[d], b2 = we[d];
            acc += a2.x * b2.x + a2.y * b2.y + a2.z * b2.z + a2.w * b2.w;
        }
        float r = tanh_fast(acc);
        ((float*)rs4)[h] = r;
        r_out[m * HP + h] = r;
    }
    __syncthreads();
    if (h < HP) {
        const float4* wc = (const float4*)(Wc + h * HP);
        const float4* wo = (const float4*)(Wo + h * HP);
        float accc = 0.f, acco = 0.f;
        #pragma unroll
        for (int q = 0; q < 25; ++q) {
            float4 r = rs4[q], cc = wc[q], oo = wo[q];
            accc += r.x * cc.x + r.y * cc.y + r.z * cc.z + r.w * cc.w;
            acco += r.x * oo.x + r.y * oo.y + r.z * oo.z + r.w * oo.w;
        }
        c_ws[m * HP + h] = accc;
        o_ws[m * HP + h] = acco;
    }
}

// ---------------- Node 2: V + E + alpha + s_rows (blocks 0..254) + scs -----
__global__ __launch_bounds__(256) void node2_kernel(const float* __restrict__ Sp,
                                                    const int* __restrict__ spans,
                                                    const float* __restrict__ c_ws,
                                                    const float* __restrict__ o_ws,
                                                    const float* __restrict__ Wv,
                                                    float* __restrict__ V_out,
                                                    float* __restrict__ s_ws,
                                                    fx4* __restrict__ out4) {
    if (blockIdx.x >= MM1) {
        scs_slice((const fx4*)Sp, spans, out4, NB2 + blockIdx.x - MM1);
        return;
    }
    __shared__ float4 olo4[25], ohi4[25], wv4[25];
    __shared__ float part[4];
    int jp = blockIdx.x;
    int i = threadIdx.x;
    if (i < 25) {
        olo4[i] = ((const float4*)(o_ws + jp * HP))[i];
        ohi4[i] = ((const float4*)(o_ws + (jp + 1) * HP))[i];
        wv4[i]  = ((const float4*)Wv)[i];
    }
    __syncthreads();

    const float4* c4p = (const float4*)(c_ws + i * HP);
    bool hi = (jp >= i);
    float acc = 0.f;
    #pragma unroll
    for (int q = 0; q < 25; ++q) {
        float4 c4 = c4p[q];
        float4 o4 = hi ? ohi4[q] : olo4[q];
        float4 w4 = wv4[q];
        acc += tanh_fast(c4.x + o4.x) * w4.x;
        acc += tanh_fast(c4.y + o4.y) * w4.y;
        acc += tanh_fast(c4.z + o4.z) * w4.z;
        acc += tanh_fast(c4.w + o4.w) * w4.w;
    }
    V_out[i * MM1 + jp] = acc;
    float e = __expf(acc);

    float v = e;
    v += __shfl_down(v, 32); v += __shfl_down(v, 16); v += __shfl_down(v, 8);
    v += __shfl_down(v, 4);  v += __shfl_down(v, 2);  v += __shfl_down(v, 1);
    if ((i & 63) == 0) part[i >> 6] = v;
    __syncthreads();
    float colE = part[0] + part[1] + part[2] + part[3];

    float a = e / (colE - e);

    __syncthreads();
    float v2 = a;
    v2 += __shfl_down(v2, 32); v2 += __shfl_down(v2, 16); v2 += __shfl_down(v2, 8);
    v2 += __shfl_down(v2, 4);  v2 += __shfl_down(v2, 2);  v2 += __shfl_down(v2, 1);
    if ((i & 63) == 0) part[i >> 6] = v2;
    __syncthreads();
    float colA = part[0] + part[1] + part[2] + part[3];

    s_ws[i * MM1 + jp] = colA - a;
}

// ---------------- Node 3: tilda (blocks 0..255) + scs slice ----------------
__global__ __launch_bounds__(256) void node3_kernel(const float* __restrict__ Sp,
                                                    const int* __restrict__ spans,
                                                    const float* __restrict__ s_ws,
                                                    const float* __restrict__ r_out,
                                                    float* __restrict__ til_out,
                                                    fx4* __restrict__ out4) {
    if (blockIdx.x >= MP) {
        scs_slice((const fx4*)Sp, spans, out4, NB3 + blockIdx.x - MP);
        return;
    }
    __shared__ float s[MM1 + 1];
    int i = blockIdx.x;
    for (int jp = threadIdx.x; jp < MM1; jp += 256)
        s[jp] = s_ws[i * MM1 + jp];
    __syncthreads();
    int h = threadIdx.x;
    if (h < HP) {
        float acc = 0.f;
        #pragma unroll 4
        for (int jp = 0; jp < i; ++jp)
            acc += s[jp] * r_out[jp * HP + h];
        #pragma unroll 4
        for (int jp = i; jp < MM1; ++jp)
            acc += s[jp] * r_out[(jp + 1) * HP + h];
        til_out[i * HP + h] = acc;
    }
}

extern "C" void kernel_launch(void* const* d_in, const int* in_sizes, int n_in,
                              void* d_out, int out_size, void* d_ws, size_t ws_size,
                              hipStream_t stream) {
    const float* S_p      = (const float*)d_in[0];
    const int*   spans    = (const int*)d_in[1];
    const int*   passages = (const int*)d_in[2];
    const float* Wb       = (const float*)d_in[3];
    const float* We       = (const float*)d_in[4];
    const float* Wc       = (const float*)d_in[5];
    const float* Wo       = (const float*)d_in[6];
    const float* Wv       = (const float*)d_in[7];

    float* out = (float*)d_out;
    float* ws  = (float*)d_ws;

    float* out_scs = out + OFF_SCS;
    float* out_r   = out + OFF_R;
    float* out_enc = out + OFF_ENC;
    float* out_v   = out + OFF_V;
    float* out_til = out + OFF_TIL;

    float* ws_c = ws + WS_C;
    float* ws_o = ws + WS_O;
    float* ws_s = ws + WS_S;

    fx4* out4 = (fx4*)out_scs;

    node1_kernel<<<MP + SCS_B1, 256, 0, stream>>>(S_p, spans, passages,
                                                  Wb, We, Wc, Wo,
                                                  out_enc, out_r, ws_c, ws_o, out4);
    node2_kernel<<<MM1 + SCS_B2, 256, 0, stream>>>(S_p, spans, ws_c, ws_o, Wv,
                                                   out_v, ws_s, out4);
    node3_kernel<<<MP + SCS_B3, 256, 0, stream>>>(S_p, spans, ws_s, out_r,
                                                  out_til, out4);
}